// Round 13
// baseline (75.534 us; speedup 1.0000x reference)
//
#include <hip/hip_runtime.h>
#include <stdint.h>

typedef __attribute__((ext_vector_type(8))) short  short8;
typedef __attribute__((ext_vector_type(4))) float  f32x4;

static __device__ __forceinline__ uint32_t f2bf(float x) {
    union { float f; uint32_t u; } v; v.f = x;
    return (v.u + 0x7FFFu + ((v.u >> 16) & 1u)) >> 16;
}

// Fragment-order layout for a 16x32 bf16 MFMA operand tile:
//   frag[(tile*NKS + ks)*512 + lane*8 + e]  where lane = row16 + 16*kh, k = ks*32 + kh*8 + e

// ---------------- kernel 0: weights prep
__global__ __launch_bounds__(256) void prep_weights(
    const float* __restrict__ W2, const float* __restrict__ W1,
    uint16_t* __restrict__ W2f, uint16_t* __restrict__ W1f) {
    int bid = blockIdx.x, t = threadIdx.x;
    if (bid < 512) {
        int idx = bid * 256 + t;              // 0..131071
        int f  = idx >> 10;
        int kd = idx & 1023;
        int d = kd >> 5, c = kd & 31;
        int ftile = f >> 4, l16 = f & 15;
        int ks = kd >> 5, kh = (kd >> 3) & 3, e = kd & 7;
        W2f[(size_t)(ftile * 32 + ks) * 512 + (l16 + 16 * kh) * 8 + e] =
            (uint16_t)f2bf(W2[f * 1024 + c * 32 + d]);
    } else {
        int idx = (bid - 512) * 256 + t;      // 0..8191
        int f = idx >> 7, c = idx & 127;
        int ftile = f >> 4, l16 = f & 15;
        int ks = c >> 5, kh = (c >> 3) & 3, e = c & 7;
        W1f[(size_t)(ftile * 4 + ks) * 512 + (l16 + 16 * kh) * 8 + e] =
            (uint16_t)f2bf(W1[f * 128 + c]);
    }
}

// ---------------- kernel 1: LayerNorm + proj via MFMA -> At/Bt fragment order
// At carries proj/128 (OPM scale folded in); Bt carries raw proj.
__global__ __launch_bounds__(256) void ln_proj(
    const float* __restrict__ mI, const float* __restrict__ lnw,
    const float* __restrict__ lnb, const uint16_t* __restrict__ W1f,
    const float* __restrict__ b1,
    uint16_t* __restrict__ At, uint16_t* __restrict__ Bt)
{
    __shared__ __align__(16) uint16_t mns[256 * 8];   // 4 KB, granule-swizzled
    const int t = threadIdx.x;
    const int bid = blockIdx.x;
    const int i0 = (bid * 16) & 255;
    const int r  = bid >> 4;

    {
        int row = t >> 4, cb = t & 15;
        const float* rp = mI + ((size_t)bid * 16 + row) * 128 + cb * 8;
        float4 v0 = *(const float4*)(rp);
        float4 v1 = *(const float4*)(rp + 4);
        float s  = v0.x + v0.y + v0.z + v0.w + v1.x + v1.y + v1.z + v1.w;
        float ss = v0.x*v0.x + v0.y*v0.y + v0.z*v0.z + v0.w*v0.w
                 + v1.x*v1.x + v1.y*v1.y + v1.z*v1.z + v1.w*v1.w;
        #pragma unroll
        for (int off = 8; off > 0; off >>= 1) {
            s  += __shfl_xor(s, off);
            ss += __shfl_xor(ss, off);
        }
        float mean = s * (1.0f / 128.0f);
        float var  = ss * (1.0f / 128.0f) - mean * mean;
        float rstd = rsqrtf(var + 1e-5f);
        float4 wa = *(const float4*)(lnw + cb * 8);
        float4 wb = *(const float4*)(lnw + cb * 8 + 4);
        float4 ba = *(const float4*)(lnb + cb * 8);
        float4 bb = *(const float4*)(lnb + cb * 8 + 4);
        uint16_t y[8];
        y[0] = (uint16_t)f2bf((v0.x - mean) * rstd * wa.x + ba.x);
        y[1] = (uint16_t)f2bf((v0.y - mean) * rstd * wa.y + ba.y);
        y[2] = (uint16_t)f2bf((v0.z - mean) * rstd * wa.z + ba.z);
        y[3] = (uint16_t)f2bf((v0.w - mean) * rstd * wa.w + ba.w);
        y[4] = (uint16_t)f2bf((v1.x - mean) * rstd * wb.x + bb.x);
        y[5] = (uint16_t)f2bf((v1.y - mean) * rstd * wb.y + bb.y);
        y[6] = (uint16_t)f2bf((v1.z - mean) * rstd * wb.z + bb.z);
        y[7] = (uint16_t)f2bf((v1.w - mean) * rstd * wb.w + bb.w);
        int g = cb * 16 + (row ^ (cb & 7));           // swizzled granule
        *(uint2*)&mns[g * 8]     = *(uint2*)&y[0];
        *(uint2*)&mns[g * 8 + 4] = *(uint2*)&y[4];
    }
    __syncthreads();

    const int w = t >> 6, l = t & 63;
    const int l16 = l & 15, lh = l >> 4;
    f32x4 acc = (f32x4)(0.0f);
    #pragma unroll
    for (int ks = 0; ks < 4; ++ks) {
        int cb = ks * 4 + lh;
        int g  = cb * 16 + (l16 ^ (cb & 7));
        short8 a = *(const short8*)&mns[g * 8];
        short8 b = *(const short8*)(W1f + (size_t)(w * 4 + ks) * 512 + l * 8);
        acc = __builtin_amdgcn_mfma_f32_16x16x32_bf16(a, b, acc, 0, 0, 0);
    }
    float b1v = b1[w * 16 + l16];
    uint16_t* dst = (w < 2) ? At : Bt;
    const float scale = (w < 2) ? (1.0f / 128.0f) : 1.0f;   // fold OPM /128 into At
    const int cch = w & 1;
    const int base2 = (r >> 5) * 512 + (l16 + 16 * ((r >> 3) & 3)) * 8 + (r & 7);
    #pragma unroll
    for (int v = 0; v < 4; ++v) {
        int i = i0 + lh * 4 + v;
        int mtile = i * 2 + cch;
        dst[(size_t)mtile * 2048 + base2] = (uint16_t)f2bf((acc[v] + b1v) * scale);
    }
}

// ---------------- kernel 2: fused OPM GEMM + MFMA W2 epilogue (256x128 tile)
// Grid (64,32). 512 thr, 8 waves. Main: C[256ic][128jd], wave (wm,wn) does 64x64.
// LDS:  Out in FRAGMENT ORDER [pt=2][ks=32][lane*8] bf16, ks-XOR swizzled (64 KB dynamic)
// Epi:  (2f,1pt) split — wave w: pt = w&1, f-tiles {2(w>>1), 2(w>>1)+1};
//       per ks: 2 W-frags (global, prefetch 4) + 1 o-frag (LDS) -> 2 MFMAs.
extern __shared__ uint16_t outl[];
__global__ __launch_bounds__(512, 4) void fused_opm(
    const uint16_t* __restrict__ At, const uint16_t* __restrict__ Bt,
    const uint16_t* __restrict__ W2f, const float* __restrict__ b2,
    float* __restrict__ z)
{
    const int t = threadIdx.x;
    const int w = t >> 6, l = t & 63;
    const int l16 = l & 15, lh = l >> 4;
    const int bx = blockIdx.x, by = blockIdx.y;
    const int wm = w >> 1, wn = w & 1;

    // ---- main GEMM: contiguous 1KB/wave fragment loads ----
    f32x4 acc[4][4];
    #pragma unroll
    for (int a = 0; a < 4; ++a)
        #pragma unroll
        for (int b = 0; b < 4; ++b) acc[a][b] = (f32x4)(0.0f);

    const uint16_t* Abase = At + (size_t)(by * 16 + wm * 4) * 4 * 512 + l * 8;
    const uint16_t* Bbase = Bt + (size_t)(bx * 8 + wn * 4) * 4 * 512 + l * 8;
    #pragma unroll
    for (int ks = 0; ks < 4; ++ks) {
        short8 af[4], bf[4];
        #pragma unroll
        for (int mt = 0; mt < 4; ++mt)
            af[mt] = *(const short8*)(Abase + (size_t)(mt * 4 + ks) * 512);
        #pragma unroll
        for (int nt = 0; nt < 4; ++nt)
            bf[nt] = *(const short8*)(Bbase + (size_t)(nt * 4 + ks) * 512);
        #pragma unroll
        for (int mt = 0; mt < 4; ++mt)
            #pragma unroll
            for (int nt = 0; nt < 4; ++nt)
                acc[mt][nt] = __builtin_amdgcn_mfma_f32_16x16x32_bf16(
                    af[mt], bf[nt], acc[mt][nt], 0, 0, 0);
    }

    // ---- issue first 4+4 epilogue W-frag loads NOW (latency hides under C-write) ----
    const int pt  = w & 1;                 // epilogue p-tile
    const int ft0 = (w >> 1) * 2;          // f-tiles ft0, ft0+1
    const uint16_t* Wt0 = W2f + (size_t)(ft0    ) * 32 * 512 + l * 8;
    const uint16_t* Wt1 = W2f + (size_t)(ft0 + 1) * 32 * 512 + l * 8;
    short8 wb0[4], wb1[4];
    #pragma unroll
    for (int q = 0; q < 4; ++q) {
        wb0[q] = *(const short8*)(Wt0 + (size_t)q * 512);
        wb1[q] = *(const short8*)(Wt1 + (size_t)q * 512);
    }

    // ---- C (pre-scaled by 1/128 via At) -> bf16 -> Out LDS frag-order, ks-XOR swz ----
    // acc[mt][nt] reg v = C[ic = wm*64+mt*16+lh*4+v][jd = wn*64+nt*16+l16]
    // frag: ks = d; kh = (mt&1)*2+(lh>>1); e = (lh&1)*4 + v
    #pragma unroll
    for (int mt = 0; mt < 4; ++mt) {
        const int kh = (mt & 1) * 2 + (lh >> 1);
        const int e0 = (lh & 1) * 4;
        #pragma unroll
        for (int nt = 0; nt < 4; ++nt) {
            int p  = wm * 8 + (mt >> 1) * 4 + wn * 2 + (nt >> 1);
            int ks = (nt & 1) * 16 + l16;
            int ptw = p >> 4, l16t = p & 15;
            f32x4 v = acc[mt][nt];
            uint2 pk;
            pk.x = f2bf(v[0]) | (f2bf(v[1]) << 16);
            pk.y = f2bf(v[2]) | (f2bf(v[3]) << 16);
            uint32_t byte = (uint32_t)(ptw * 32 + ks) * 1024u
                          + (uint32_t)(l16t + 16 * kh) * 16u + (uint32_t)e0 * 2u;
            byte ^= (uint32_t)(ks & 7) << 4;
            *(uint2*)((char*)outl + byte) = pk;
        }
    }
    __syncthreads();

    // ---- epilogue: per ks, 1 LDS o-frag feeds 2 MFMAs (2 f-tiles) ----
    f32x4 zacc0[2], zacc1[2];
    zacc0[0] = (f32x4)(0.0f); zacc0[1] = (f32x4)(0.0f);
    zacc1[0] = (f32x4)(0.0f); zacc1[1] = (f32x4)(0.0f);

    #pragma unroll
    for (int ks = 0; ks < 32; ++ks) {
        short8 cw0 = wb0[ks & 3];
        short8 cw1 = wb1[ks & 3];
        if (ks < 28) {
            wb0[ks & 3] = *(const short8*)(Wt0 + (size_t)(ks + 4) * 512);
            wb1[ks & 3] = *(const short8*)(Wt1 + (size_t)(ks + 4) * 512);
        }
        uint32_t ob = ((uint32_t)(pt * 32 + ks) * 1024u + (uint32_t)l * 16u)
                    ^ ((uint32_t)(ks & 7) << 4);
        short8 o = *(const short8*)((const char*)outl + ob);
        zacc0[ks & 1] = __builtin_amdgcn_mfma_f32_16x16x32_bf16(cw0, o, zacc0[ks & 1], 0, 0, 0);
        zacc1[ks & 1] = __builtin_amdgcn_mfma_f32_16x16x32_bf16(cw1, o, zacc1[ks & 1], 0, 0, 0);
    }

    // ---- write z: lane p = pt*16+l16; f rows (ft0|ft0+1)*16 + lh*4 ----
    const int p  = pt * 16 + l16;
    const int zi = by * 8 + (p >> 2);
    const int zj = bx * 4 + (p & 3);
    float* zrow = z + ((size_t)zi * 256 + zj) * 128;
    {
        int f0 = ft0 * 16 + lh * 4;
        float4 bv = *(const float4*)(b2 + f0);
        float4 zr;
        zr.x = zacc0[0][0] + zacc0[1][0] + bv.x;
        zr.y = zacc0[0][1] + zacc0[1][1] + bv.y;
        zr.z = zacc0[0][2] + zacc0[1][2] + bv.z;
        zr.w = zacc0[0][3] + zacc0[1][3] + bv.w;
        *(float4*)(zrow + f0) = zr;
    }
    {
        int f0 = (ft0 + 1) * 16 + lh * 4;
        float4 bv = *(const float4*)(b2 + f0);
        float4 zr;
        zr.x = zacc1[0][0] + zacc1[1][0] + bv.x;
        zr.y = zacc1[0][1] + zacc1[1][1] + bv.y;
        zr.z = zacc1[0][2] + zacc1[1][2] + bv.z;
        zr.w = zacc1[0][3] + zacc1[1][3] + bv.w;
        *(float4*)(zrow + f0) = zr;
    }
}

extern "C" void kernel_launch(void* const* d_in, const int* in_sizes, int n_in,
                              void* d_out, int out_size, void* d_ws, size_t ws_size,
                              hipStream_t stream) {
    const float* m_in = (const float*)d_in[0];
    const float* ln_w = (const float*)d_in[1];
    const float* ln_b = (const float*)d_in[2];
    const float* W1   = (const float*)d_in[3];
    const float* b1   = (const float*)d_in[4];
    const float* W2   = (const float*)d_in[5];
    const float* b2   = (const float*)d_in[6];
    float* z = (float*)d_out;

    uint16_t* At  = (uint16_t*)d_ws;                 // 2 MB
    uint16_t* Bt  = At + 8192 * 128;                 // 2 MB
    uint16_t* W2f = Bt + 8192 * 128;                 // 256 KB
    uint16_t* W1f = W2f + 128 * 1024;                // 16 KB

    prep_weights<<<544, 256, 0, stream>>>(W2, W1, W2f, W1f);
    ln_proj<<<2048, 256, 0, stream>>>(m_in, ln_w, ln_b, W1f, b1, At, Bt);
    fused_opm<<<dim3(64, 32), 512, 64 * 1024, stream>>>(At, Bt, W2f, b2, z);
}

// Round 14
// 63.346 us; speedup vs baseline: 1.1924x; 1.1924x over previous
//
#include <hip/hip_runtime.h>
#include <stdint.h>

typedef __attribute__((ext_vector_type(8))) short  short8;
typedef __attribute__((ext_vector_type(4))) float  f32x4;

static __device__ __forceinline__ uint32_t f2bf(float x) {
    union { float f; uint32_t u; } v; v.f = x;
    return (v.u + 0x7FFFu + ((v.u >> 16) & 1u)) >> 16;
}

// Fragment-order layout for a 16x32 bf16 MFMA operand tile:
//   frag[(tile*NKS + ks)*512 + lane*8 + e]  where lane = row16 + 16*kh, k = ks*32 + kh*8 + e

// ---------------- kernel 0: weights prep
__global__ __launch_bounds__(256) void prep_weights(
    const float* __restrict__ W2, const float* __restrict__ W1,
    uint16_t* __restrict__ W2f, uint16_t* __restrict__ W1f) {
    int bid = blockIdx.x, t = threadIdx.x;
    if (bid < 512) {
        int idx = bid * 256 + t;              // 0..131071
        int f  = idx >> 10;
        int kd = idx & 1023;
        int d = kd >> 5, c = kd & 31;
        int ftile = f >> 4, l16 = f & 15;
        int ks = kd >> 5, kh = (kd >> 3) & 3, e = kd & 7;
        W2f[(size_t)(ftile * 32 + ks) * 512 + (l16 + 16 * kh) * 8 + e] =
            (uint16_t)f2bf(W2[f * 1024 + c * 32 + d]);
    } else {
        int idx = (bid - 512) * 256 + t;      // 0..8191
        int f = idx >> 7, c = idx & 127;
        int ftile = f >> 4, l16 = f & 15;
        int ks = c >> 5, kh = (c >> 3) & 3, e = c & 7;
        W1f[(size_t)(ftile * 4 + ks) * 512 + (l16 + 16 * kh) * 8 + e] =
            (uint16_t)f2bf(W1[f * 128 + c]);
    }
}

// ---------------- kernel 1: LayerNorm + proj via MFMA -> At/Bt fragment order
// At carries proj/128 (OPM scale folded in); Bt carries raw proj.
__global__ __launch_bounds__(256) void ln_proj(
    const float* __restrict__ mI, const float* __restrict__ lnw,
    const float* __restrict__ lnb, const uint16_t* __restrict__ W1f,
    const float* __restrict__ b1,
    uint16_t* __restrict__ At, uint16_t* __restrict__ Bt)
{
    __shared__ __align__(16) uint16_t mns[256 * 8];   // 4 KB, granule-swizzled
    const int t = threadIdx.x;
    const int bid = blockIdx.x;
    const int i0 = (bid * 16) & 255;
    const int r  = bid >> 4;

    {
        int row = t >> 4, cb = t & 15;
        const float* rp = mI + ((size_t)bid * 16 + row) * 128 + cb * 8;
        float4 v0 = *(const float4*)(rp);
        float4 v1 = *(const float4*)(rp + 4);
        float s  = v0.x + v0.y + v0.z + v0.w + v1.x + v1.y + v1.z + v1.w;
        float ss = v0.x*v0.x + v0.y*v0.y + v0.z*v0.z + v0.w*v0.w
                 + v1.x*v1.x + v1.y*v1.y + v1.z*v1.z + v1.w*v1.w;
        #pragma unroll
        for (int off = 8; off > 0; off >>= 1) {
            s  += __shfl_xor(s, off);
            ss += __shfl_xor(ss, off);
        }
        float mean = s * (1.0f / 128.0f);
        float var  = ss * (1.0f / 128.0f) - mean * mean;
        float rstd = rsqrtf(var + 1e-5f);
        float4 wa = *(const float4*)(lnw + cb * 8);
        float4 wb = *(const float4*)(lnw + cb * 8 + 4);
        float4 ba = *(const float4*)(lnb + cb * 8);
        float4 bb = *(const float4*)(lnb + cb * 8 + 4);
        uint16_t y[8];
        y[0] = (uint16_t)f2bf((v0.x - mean) * rstd * wa.x + ba.x);
        y[1] = (uint16_t)f2bf((v0.y - mean) * rstd * wa.y + ba.y);
        y[2] = (uint16_t)f2bf((v0.z - mean) * rstd * wa.z + ba.z);
        y[3] = (uint16_t)f2bf((v0.w - mean) * rstd * wa.w + ba.w);
        y[4] = (uint16_t)f2bf((v1.x - mean) * rstd * wb.x + bb.x);
        y[5] = (uint16_t)f2bf((v1.y - mean) * rstd * wb.y + bb.y);
        y[6] = (uint16_t)f2bf((v1.z - mean) * rstd * wb.z + bb.z);
        y[7] = (uint16_t)f2bf((v1.w - mean) * rstd * wb.w + bb.w);
        int g = cb * 16 + (row ^ (cb & 7));           // swizzled granule
        *(uint2*)&mns[g * 8]     = *(uint2*)&y[0];
        *(uint2*)&mns[g * 8 + 4] = *(uint2*)&y[4];
    }
    __syncthreads();

    const int w = t >> 6, l = t & 63;
    const int l16 = l & 15, lh = l >> 4;
    f32x4 acc = (f32x4)(0.0f);
    #pragma unroll
    for (int ks = 0; ks < 4; ++ks) {
        int cb = ks * 4 + lh;
        int g  = cb * 16 + (l16 ^ (cb & 7));
        short8 a = *(const short8*)&mns[g * 8];
        short8 b = *(const short8*)(W1f + (size_t)(w * 4 + ks) * 512 + l * 8);
        acc = __builtin_amdgcn_mfma_f32_16x16x32_bf16(a, b, acc, 0, 0, 0);
    }
    float b1v = b1[w * 16 + l16];
    uint16_t* dst = (w < 2) ? At : Bt;
    const float scale = (w < 2) ? (1.0f / 128.0f) : 1.0f;   // fold OPM /128 into At
    const int cch = w & 1;
    const int base2 = (r >> 5) * 512 + (l16 + 16 * ((r >> 3) & 3)) * 8 + (r & 7);
    #pragma unroll
    for (int v = 0; v < 4; ++v) {
        int i = i0 + lh * 4 + v;
        int mtile = i * 2 + cch;
        dst[(size_t)mtile * 2048 + base2] = (uint16_t)f2bf((acc[v] + b1v) * scale);
    }
}

// ---------------- kernel 2: fused OPM GEMM + MFMA W2 epilogue (256x128 tile)
// Grid (64,32). 512 thr, 8 waves. Main: C[256ic][128jd], wave (wm,wn) does 64x64.
// LDS:  Out in FRAGMENT ORDER [pt=2][ks=32][lane*8] bf16, ks-XOR swizzled (64 KB dynamic)
// Epi:  wave w = f-tile w, 2 p-tiles, 32 ks; W-prefetch depth 8, o-frag prefetch depth 2.
extern __shared__ uint16_t outl[];
__global__ __launch_bounds__(512, 4) void fused_opm(
    const uint16_t* __restrict__ At, const uint16_t* __restrict__ Bt,
    const uint16_t* __restrict__ W2f, const float* __restrict__ b2,
    float* __restrict__ z)
{
    const int t = threadIdx.x;
    const int w = t >> 6, l = t & 63;
    const int l16 = l & 15, lh = l >> 4;
    const int bx = blockIdx.x, by = blockIdx.y;
    const int wm = w >> 1, wn = w & 1;

    // ---- main GEMM: contiguous 1KB/wave fragment loads ----
    f32x4 acc[4][4];
    #pragma unroll
    for (int a = 0; a < 4; ++a)
        #pragma unroll
        for (int b = 0; b < 4; ++b) acc[a][b] = (f32x4)(0.0f);

    const uint16_t* Abase = At + (size_t)(by * 16 + wm * 4) * 4 * 512 + l * 8;
    const uint16_t* Bbase = Bt + (size_t)(bx * 8 + wn * 4) * 4 * 512 + l * 8;
    #pragma unroll
    for (int ks = 0; ks < 4; ++ks) {
        short8 af[4], bf[4];
        #pragma unroll
        for (int mt = 0; mt < 4; ++mt)
            af[mt] = *(const short8*)(Abase + (size_t)(mt * 4 + ks) * 512);
        #pragma unroll
        for (int nt = 0; nt < 4; ++nt)
            bf[nt] = *(const short8*)(Bbase + (size_t)(nt * 4 + ks) * 512);
        #pragma unroll
        for (int mt = 0; mt < 4; ++mt)
            #pragma unroll
            for (int nt = 0; nt < 4; ++nt)
                acc[mt][nt] = __builtin_amdgcn_mfma_f32_16x16x32_bf16(
                    af[mt], bf[nt], acc[mt][nt], 0, 0, 0);
    }

    // ---- issue first 8 epilogue W-frag loads NOW (latency hides under C-write) ----
    const uint16_t* Wt = W2f + (size_t)w * 32 * 512 + l * 8;
    short8 wbuf[8];
    #pragma unroll
    for (int q = 0; q < 8; ++q)
        wbuf[q] = *(const short8*)(Wt + (size_t)q * 512);

    // ---- C (pre-scaled by 1/128 via At) -> bf16 -> Out LDS frag-order, ks-XOR swz ----
    // acc[mt][nt] reg v = C[ic = wm*64+mt*16+lh*4+v][jd = wn*64+nt*16+l16]
    // frag: ks = d; kh = (mt&1)*2+(lh>>1); e = (lh&1)*4 + v
    #pragma unroll
    for (int mt = 0; mt < 4; ++mt) {
        const int kh = (mt & 1) * 2 + (lh >> 1);
        const int e0 = (lh & 1) * 4;
        #pragma unroll
        for (int nt = 0; nt < 4; ++nt) {
            int p  = wm * 8 + (mt >> 1) * 4 + wn * 2 + (nt >> 1);
            int ks = (nt & 1) * 16 + l16;
            int ptw = p >> 4, l16t = p & 15;
            f32x4 v = acc[mt][nt];
            uint2 pk;
            pk.x = f2bf(v[0]) | (f2bf(v[1]) << 16);
            pk.y = f2bf(v[2]) | (f2bf(v[3]) << 16);
            uint32_t byte = (uint32_t)(ptw * 32 + ks) * 1024u
                          + (uint32_t)(l16t + 16 * kh) * 16u + (uint32_t)e0 * 2u;
            byte ^= (uint32_t)(ks & 7) << 4;
            *(uint2*)((char*)outl + byte) = pk;
        }
    }
    __syncthreads();

    // ---- epilogue: wave w = f-tile w; 2 p-tiles; 32 ks ----
    // W prefetch depth 8 (global), o-frag prefetch depth 2 (LDS).
    f32x4 zacc[2][2];
    #pragma unroll
    for (int a = 0; a < 2; ++a) { zacc[a][0] = (f32x4)(0.0f); zacc[a][1] = (f32x4)(0.0f); }

    const char* outb = (const char*)outl;
    #define OB0(ksv) ((((uint32_t)(ksv) * 1024u + (uint32_t)l * 16u)) ^ ((uint32_t)((ksv) & 7) << 4))
    #define OB1(ksv) ((((uint32_t)(32 + (ksv)) * 1024u + (uint32_t)l * 16u)) ^ ((uint32_t)((ksv) & 7) << 4))

    short8 o0c = *(const short8*)(outb + OB0(0));
    short8 o1c = *(const short8*)(outb + OB1(0));
    #pragma unroll
    for (int ks = 0; ks < 32; ++ks) {
        short8 cw = wbuf[ks & 7];
        if (ks < 24) wbuf[ks & 7] = *(const short8*)(Wt + (size_t)(ks + 8) * 512);
        short8 o0 = o0c, o1 = o1c;
        if (ks < 31) {
            o0c = *(const short8*)(outb + OB0(ks + 1));
            o1c = *(const short8*)(outb + OB1(ks + 1));
        }
        zacc[0][ks & 1] = __builtin_amdgcn_mfma_f32_16x16x32_bf16(cw, o0, zacc[0][ks & 1], 0, 0, 0);
        zacc[1][ks & 1] = __builtin_amdgcn_mfma_f32_16x16x32_bf16(cw, o1, zacc[1][ks & 1], 0, 0, 0);
    }
    #undef OB0
    #undef OB1

    // ---- write z: lane p = pt*16+l16, rows f0 = w*16+lh*4 ----
    const int f0 = w * 16 + lh * 4;
    const float4 bv = *(const float4*)(b2 + f0);
    #pragma unroll
    for (int pt = 0; pt < 2; ++pt) {
        int p  = pt * 16 + l16;
        int zi = by * 8 + (p >> 2);
        int zj = bx * 4 + (p & 3);
        float* zrow = z + ((size_t)zi * 256 + zj) * 128;
        float4 zr;
        zr.x = zacc[pt][0][0] + zacc[pt][1][0] + bv.x;
        zr.y = zacc[pt][0][1] + zacc[pt][1][1] + bv.y;
        zr.z = zacc[pt][0][2] + zacc[pt][1][2] + bv.z;
        zr.w = zacc[pt][0][3] + zacc[pt][1][3] + bv.w;
        *(float4*)(zrow + f0) = zr;
    }
}

extern "C" void kernel_launch(void* const* d_in, const int* in_sizes, int n_in,
                              void* d_out, int out_size, void* d_ws, size_t ws_size,
                              hipStream_t stream) {
    const float* m_in = (const float*)d_in[0];
    const float* ln_w = (const float*)d_in[1];
    const float* ln_b = (const float*)d_in[2];
    const float* W1   = (const float*)d_in[3];
    const float* b1   = (const float*)d_in[4];
    const float* W2   = (const float*)d_in[5];
    const float* b2   = (const float*)d_in[6];
    float* z = (float*)d_out;

    uint16_t* At  = (uint16_t*)d_ws;                 // 2 MB
    uint16_t* Bt  = At + 8192 * 128;                 // 2 MB
    uint16_t* W2f = Bt + 8192 * 128;                 // 256 KB
    uint16_t* W1f = W2f + 128 * 1024;                // 16 KB

    prep_weights<<<544, 256, 0, stream>>>(W2, W1, W2f, W1f);
    ln_proj<<<2048, 256, 0, stream>>>(m_in, ln_w, ln_b, W1f, b1, At, Bt);
    fused_opm<<<dim3(64, 32), 512, 64 * 1024, stream>>>(At, Bt, W2f, b2, z);
}